// Round 4
// baseline (85.686 us; speedup 1.0000x reference)
//
#include <hip/hip_runtime.h>
#include <math.h>

#define BB   8
#define NN   96
#define DD   16
#define H0D  50
#define H1D  50
#define OUTD 64
#define XP   17

typedef unsigned long long u64;

// W1: (51,50): rows 0-15 Wxi, 16-31 Wxj, 32-47 Wxk, 48 w_ij, 49 w_jk, 50 w_ik
// W2: (83,50): rows 0-15 xi, 16-31 xj, 32 dis, 33-82 m3
// W3: (66,64)

__global__ __launch_bounds__(256) void sgc_one(
    const float* __restrict__ x, const float* __restrict__ adj,
    const float* __restrict__ W1, const float* __restrict__ b1,
    const float* __restrict__ W2, const float* __restrict__ b2,
    const float* __restrict__ W3, const float* __restrict__ b3,
    float* __restrict__ out)
{
    const int b = blockIdx.x / NN, i = blockIdx.x % NN;
    const int tid = threadIdx.x, wv = tid >> 6, lane = tid & 63;

    __shared__ float sx[NN * XP];        // x[b], padded
    __shared__ float sdisI[NN];          // dis row i
    __shared__ int   nbrs[NN];           // neighbor list of i
    __shared__ int   scnt;
    __shared__ u64   smi[2];             // mask_i
    __shared__ float sA[H0D];            // A_i = x_i @ Wxi
    __shared__ float sP[NN * H0D];       // per-neighbor P_j
    __shared__ float sdegc[NN], ssdjkc[NN], ssdikc[NN];
    __shared__ float pmsum[4 * 64];
    __shared__ float smsum[H0D];
    __shared__ float sm2[H1D];
    __shared__ float snxi[DD];
    __shared__ float sdegi, ssdjki;

    // ---- phase 0: stage x[b]; wave 0 builds mask_i + neighbor list ----
    const float4* x4 = (const float4*)(x + (size_t)b * NN * DD);
    for (int t = tid; t < NN * DD / 4; t += 256) {
        float4 v = x4[t];
        int row = t >> 2, d = (t & 3) * 4;
        float* p = &sx[row * XP + d];
        p[0] = v.x; p[1] = v.y; p[2] = v.z; p[3] = v.w;
    }
    if (wv == 0) {
        const float* arow = adj + ((size_t)b * NN + i) * NN;
        u64 m0 = __ballot(arow[lane] != 0.f);
        float a1 = (lane < 32) ? arow[64 + lane] : 0.f;
        u64 m1 = __ballot(a1 != 0.f);
        int c0 = __popcll(m0);
        if ((m0 >> lane) & 1)
            nbrs[__popcll(m0 & ((1ull << lane) - 1))] = lane;
        if (lane < 32 && ((m1 >> lane) & 1))
            nbrs[c0 + __popcll(m1 & ((1ull << lane) - 1))] = 64 + lane;
        if (lane == 0) {
            int c = c0 + __popcll(m1);
            scnt = c;
            smi[0] = m0; smi[1] = m1;
            sdegi = (float)c;
        }
    }
    __syncthreads();

    // ---- phase 1: dis row i; A_i ----
    if (tid < NN) {
        const float* xi = &sx[i * XP];
        const float* xk = &sx[tid * XP];
        float s = 1e-10f;
        #pragma unroll
        for (int d = 0; d < DD; ++d) { float t = xi[d] - xk[d]; s += t * t; }
        sdisI[tid] = sqrtf(s);
    } else if (tid < NN + H0D) {
        int h = tid - NN;
        float s = 0.f;
        #pragma unroll
        for (int d = 0; d < DD; ++d) s += sx[i * XP + d] * W1[d * H0D + h];
        sA[h] = s;
    }
    __syncthreads();

    // ---- phase 2: per-wave neighbor recompute ----
    const int cnt = scnt;
    {
        const int hl = (lane < H0D) ? lane : H0D - 1;
        float wxj[DD], wxk[DD];
        #pragma unroll
        for (int d = 0; d < DD; ++d) {
            wxj[d] = W1[(DD + d) * H0D + hl];
            wxk[d] = W1[(2 * DD + d) * H0D + hl];
        }
        const int ch = lane >> 4, dd = lane & 15;
        for (int c = wv; c < cnt; c += 4) {
            const int j = nbrs[c];
            const float* arow = adj + ((size_t)b * NN + j) * NN;
            u64 mj0 = __ballot(arow[lane] != 0.f);
            float a1 = (lane < 32) ? arow[64 + lane] : 0.f;
            u64 mj1 = __ballot(a1 != 0.f);
            float deg = (float)(__popcll(mj0) + __popcll(mj1));
            const float* xj = &sx[j * XP];
            float d0, d1 = 0.f;
            {
                float s = 1e-10f;
                const float* xk = &sx[lane * XP];
                #pragma unroll
                for (int d = 0; d < DD; ++d) { float t = xj[d] - xk[d]; s += t * t; }
                d0 = sqrtf(s);
            }
            if (lane < 32) {
                float s = 1e-10f;
                const float* xk = &sx[(64 + lane) * XP];
                #pragma unroll
                for (int d = 0; d < DD; ++d) { float t = xj[d] - xk[d]; s += t * t; }
                d1 = sqrtf(s);
            }
            float p1 = ((mj0 >> lane) & 1) ? d0 : 0.f;          // -> sd_jk[j]
            float p2 = ((mj0 >> lane) & 1) ? sdisI[lane] : 0.f;  // -> sd_ik[i,j]
            if (lane < 32 && ((mj1 >> lane) & 1)) { p1 += d1; p2 += sdisI[64 + lane]; }
            #pragma unroll
            for (int off = 1; off < 64; off <<= 1) {
                p1 += __shfl_xor(p1, off, 64);
                p2 += __shfl_xor(p2, off, 64);
            }
            // nx_j[d] via 4x24-bit chunk walk
            unsigned sm;
            if (ch == 0)      sm = (unsigned)(mj0 & 0xFFFFFFu);
            else if (ch == 1) sm = (unsigned)((mj0 >> 24) & 0xFFFFFFu);
            else if (ch == 2) sm = (unsigned)((mj0 >> 48) & 0xFFFFu) | ((unsigned)(mj1 & 0xFFu) << 16);
            else              sm = (unsigned)((mj1 >> 8) & 0xFFFFFFu);
            float nxv = 0.f;
            const int base = ch * 24;
            while (sm) {
                int k = base + __ffs(sm) - 1;
                sm &= sm - 1;
                nxv += sx[k * XP + dd];
            }
            nxv += __shfl_xor(nxv, 16, 64);
            nxv += __shfl_xor(nxv, 32, 64);   // all lanes: nx_j[lane&15]
            // P_j[h] = deg_j*(x_j@Wxj)[h] + (nx_j@Wxk)[h]
            float bm = 0.f, sc = 0.f;
            #pragma unroll
            for (int d = 0; d < DD; ++d) {
                bm += xj[d] * wxj[d];
                sc += __shfl(nxv, d, 64) * wxk[d];
            }
            if (lane < H0D) sP[c * H0D + lane] = deg * bm + sc;
            if (lane == 0) { sdegc[c] = deg; ssdjkc[c] = p1; ssdikc[c] = p2; }
        }
        // wave 0 extra: nx_i, sdjk_i
        if (wv == 0) {
            u64 mi0 = smi[0], mi1 = smi[1];
            float p = ((mi0 >> lane) & 1) ? sdisI[lane] : 0.f;
            if (lane < 32 && ((mi1 >> lane) & 1)) p += sdisI[64 + lane];
            #pragma unroll
            for (int off = 1; off < 64; off <<= 1) p += __shfl_xor(p, off, 64);
            if (lane == 0) ssdjki = p;
            unsigned sm;
            if (ch == 0)      sm = (unsigned)(mi0 & 0xFFFFFFu);
            else if (ch == 1) sm = (unsigned)((mi0 >> 24) & 0xFFFFFFu);
            else if (ch == 2) sm = (unsigned)((mi0 >> 48) & 0xFFFFu) | ((unsigned)(mi1 & 0xFFu) << 16);
            else              sm = (unsigned)((mi1 >> 8) & 0xFFFFFFu);
            float nxv = 0.f;
            const int base = ch * 24;
            while (sm) {
                int k = base + __ffs(sm) - 1;
                sm &= sm - 1;
                nxv += sx[k * XP + dd];
            }
            nxv += __shfl_xor(nxv, 16, 64);
            nxv += __shfl_xor(nxv, 32, 64);
            if (lane < DD) snxi[lane] = nxv;
        }
    }
    __syncthreads();

    // ---- phase 3: neighbor accumulation (lane = channel h, split over waves) ----
    {
        const int hl = (lane < H0D) ? lane : H0D - 1;
        float b1v = b1[hl];
        float wij = W1[(3 * DD + 0) * H0D + hl];
        float wjk = W1[(3 * DD + 1) * H0D + hl];
        float wik = W1[(3 * DD + 2) * H0D + hl];
        float abv = sA[hl] + b1v;
        float msum = 0.f;
        for (int c = wv; c < cnt; c += 4) {
            float S = sdegc[c] * (abv + sdisI[nbrs[c]] * wij)
                    + sP[c * H0D + hl] + ssdjkc[c] * wjk + ssdikc[c] * wik;
            msum += (S >= 0.f) ? S : 0.05f * S;
        }
        pmsum[wv * 64 + lane] = msum;
    }
    __syncthreads();

    if (tid < H0D)
        smsum[tid] = pmsum[tid] + pmsum[64 + tid] + pmsum[128 + tid] + pmsum[192 + tid];
    __syncthreads();

    // ---- phase 4: layer 2 ----
    if (tid < H1D) {
        float dg = sdegi;
        float s = dg * b2[tid];
        #pragma unroll
        for (int d = 0; d < DD; ++d)
            s += dg * sx[i * XP + d] * W2[d * H1D + tid]
               + snxi[d] * W2[(DD + d) * H1D + tid];
        s += ssdjki * W2[(2 * DD) * H1D + tid];
        for (int c = 0; c < H0D; ++c)
            s += smsum[c] * W2[(2 * DD + 1 + c) * H1D + tid];
        sm2[tid] = (s >= 0.f) ? s : 0.05f * s;
    }
    __syncthreads();

    // ---- phase 5: layer 3 + store ----
    if (tid < OUTD) {
        float s = b3[tid];
        #pragma unroll
        for (int d = 0; d < DD; ++d) s += sx[i * XP + d] * W3[d * OUTD + tid];
        for (int h = 0; h < H1D; ++h) s += sm2[h] * W3[(DD + h) * OUTD + tid];
        s = (s >= 0.f) ? s : 0.05f * s;
        out[((size_t)b * NN + i) * OUTD + tid] = s;
    }
}

extern "C" void kernel_launch(void* const* d_in, const int* in_sizes, int n_in,
                              void* d_out, int out_size, void* d_ws, size_t ws_size,
                              hipStream_t stream) {
    const float* x   = (const float*)d_in[0];
    const float* adj = (const float*)d_in[1];
    const float* W1  = (const float*)d_in[2];
    const float* b1  = (const float*)d_in[3];
    const float* W2  = (const float*)d_in[4];
    const float* b2  = (const float*)d_in[5];
    const float* W3  = (const float*)d_in[6];
    const float* b3  = (const float*)d_in[7];
    float* out = (float*)d_out;

    sgc_one<<<BB * NN, 256, 0, stream>>>(x, adj, W1, b1, W2, b2, W3, b3, out);
}